// Round 3
// baseline (209.072 us; speedup 1.0000x reference)
//
#include <hip/hip_runtime.h>

#define S_CACHE 32768
#define NQ 1024
#define D 128
#define KVB 32
#define TILES_TOTAL 1056
#define PARTIAL_BYTES 8448  // 4096 bf16 O^T + 32 f32 m + 32 f32 l

typedef float f32x4 __attribute__((ext_vector_type(4)));
typedef short s16x8 __attribute__((ext_vector_type(8)));
typedef int   i32x4 __attribute__((ext_vector_type(4)));

static __device__ __forceinline__ int cvtpk(float lo, float hi) {
  int r;
  asm("v_cvt_pk_bf16_f32 %0, %1, %2" : "=v"(r) : "v"(lo), "v"(hi));
  return r;
}
static __device__ __forceinline__ s16x8 frag4(int a, int b, int c, int d) {
  i32x4 t = {a, b, c, d};
  return __builtin_bit_cast(s16x8, t);
}
static __device__ __forceinline__ unsigned short f2bf(float x) {
  unsigned int u = __float_as_uint(x);
  u += 0x7fffu + ((u >> 16) & 1u);
  return (unsigned short)(u >> 16);
}
static __device__ __forceinline__ float bf2f(unsigned short b) {
  return __uint_as_float(((unsigned int)b) << 16);
}

// ---------------------------------------------------------------------------
// Main kernel: 1D grid of 8*ksplit blocks, 256 threads = 4 waves x 32 q.
// Block decode (XCD co-location): all 8 q-blocks of split s land on XCD s%8,
// within a 64-block dispatch window -> each split's KV fetched from HBM once.
// Swapped-operand flash attention:
//   S^T = mfma(A=K, B=Q^T); O^T = mfma(A=V^T, B=P^T); softmax lane-local.
// ---------------------------------------------------------------------------
__global__ __launch_bounds__(256, 4) void mt_attn_main(
    const float* __restrict__ qp, const float* __restrict__ knew,
    const float* __restrict__ vnew, const float* __restrict__ Kc,
    const float* __restrict__ Vc, unsigned char* __restrict__ ws,
    int ksplit)
{
  __shared__ __align__(16) unsigned char k_lds[2][8192];  // 8 frags (h,c) x 64 lanes x 16B
  __shared__ __align__(16) unsigned char v_lds[2][8192];  // 8 frags (dt)  x 64 lanes x 16B

  const int tid  = threadIdx.x;
  const int lane = tid & 63;
  const int w    = tid >> 6;
  const int g    = lane >> 4;
  const int qq   = lane & 15;

  // ---- block decode: co-locate a split's 8 q-blocks on one XCD ----
  const int n    = blockIdx.x;
  const int xcd  = n & 7;
  const int qg   = (n >> 3) & 7;
  const int sidx = n >> 6;
  const int s    = xcd + 8 * sidx;          // split id, s % 8 == xcd
  const int qg32 = qg * 4 + w;              // 0..31, 32 q-rows per wave
  const int t_st = (s * TILES_TOTAL) / ksplit;
  const int t_en = ((s + 1) * TILES_TOTAL) / ksplit;
  const int tiles_pb = t_en - t_st;
  const int kbase = t_st * KVB;

  // ---- Q fragments (B-operand): lane holds Q[q][32c+8g+i], scaled ----
  const float QSCALE = 0.0883883476483184f * 1.4426950408889634f;  // 1/sqrt(128)*log2(e)
  s16x8 qf[2][4];
#pragma unroll
  for (int u = 0; u < 2; ++u) {
    const float* qrow = qp + (size_t)(qg32 * 32 + u * 16 + qq) * D + 8 * g;
#pragma unroll
    for (int c = 0; c < 4; ++c) {
      f32x4 x0 = *(const f32x4*)(qrow + 32 * c);
      f32x4 x1 = *(const f32x4*)(qrow + 32 * c + 4);
      qf[u][c] = frag4(cvtpk(x0[0] * QSCALE, x0[1] * QSCALE),
                       cvtpk(x0[2] * QSCALE, x0[3] * QSCALE),
                       cvtpk(x1[0] * QSCALE, x1[1] * QSCALE),
                       cvtpk(x1[2] * QSCALE, x1[3] * QSCALE));
    }
  }

  f32x4 oacc[2][8];
#pragma unroll
  for (int u = 0; u < 2; ++u)
#pragma unroll
    for (int dt = 0; dt < 8; ++dt) {
      f32x4 z = {0.f, 0.f, 0.f, 0.f};
      oacc[u][dt] = z;
    }
  float mrun[2] = {-1e30f, -1e30f};
  float lrun[2] = {0.f, 0.f};

  // staging geometry: K chunks (h=0/1, c=w), V chunks (dt=w, w+4)
  const int kitr = 8 * (qq >> 2) + (qq & 3);
  const int kcol = 32 * w + 8 * g;

  f32x4 ka[4];
  float va[16];

  auto stage_load = [&](int t32) {
    const float* kb_;
    const float* vb_;
    if (t32 < S_CACHE) {
      kb_ = Kc + (size_t)t32 * D;
      vb_ = Vc + (size_t)t32 * D;
    } else {
      kb_ = knew + (size_t)(t32 - S_CACHE) * D;
      vb_ = vnew + (size_t)(t32 - S_CACHE) * D;
    }
    ka[0] = *(const f32x4*)(kb_ + (size_t)kitr * D + kcol);
    ka[1] = *(const f32x4*)(kb_ + (size_t)kitr * D + kcol + 4);
    ka[2] = *(const f32x4*)(kb_ + (size_t)(kitr + 4) * D + kcol);
    ka[3] = *(const f32x4*)(kb_ + (size_t)(kitr + 4) * D + kcol + 4);
#pragma unroll
    for (int j = 0; j < 2; ++j) {
      const int dt = w + 4 * j;
#pragma unroll
      for (int i = 0; i < 8; ++i)
        va[8 * j + i] = vb_[(size_t)(8 * g + i) * D + 16 * dt + qq];
    }
  };

  auto stage_write = [&](int b) {
    i32x4 kc0 = {cvtpk(ka[0][0], ka[0][1]), cvtpk(ka[0][2], ka[0][3]),
                 cvtpk(ka[1][0], ka[1][1]), cvtpk(ka[1][2], ka[1][3])};
    *(i32x4*)(&k_lds[b][(size_t)((w)*64 + lane) * 16]) = kc0;
    i32x4 kc1 = {cvtpk(ka[2][0], ka[2][1]), cvtpk(ka[2][2], ka[2][3]),
                 cvtpk(ka[3][0], ka[3][1]), cvtpk(ka[3][2], ka[3][3])};
    *(i32x4*)(&k_lds[b][(size_t)((4 + w) * 64 + lane) * 16]) = kc1;
#pragma unroll
    for (int j = 0; j < 2; ++j) {
      i32x4 vc = {cvtpk(va[8 * j + 0], va[8 * j + 1]), cvtpk(va[8 * j + 2], va[8 * j + 3]),
                  cvtpk(va[8 * j + 4], va[8 * j + 5]), cvtpk(va[8 * j + 6], va[8 * j + 7])};
      *(i32x4*)(&v_lds[b][(size_t)((w + 4 * j) * 64 + lane) * 16]) = vc;
    }
  };

  stage_load(kbase);
  stage_write(0);
  int cur = 0;

  for (int tile = 0; tile < tiles_pb; ++tile) {
    const int t32 = kbase + tile * KVB;
    __syncthreads();

    const bool havenext = (tile + 1 < tiles_pb);
    if (havenext) stage_load(t32 + KVB);  // issue loads early; consumed in stage_write

    // ---- QK^T (swapped): lane(g,qq) gets scores for q=qq, keys 8g+n ----
    f32x4 sc[2][2];
#pragma unroll
    for (int u = 0; u < 2; ++u)
#pragma unroll
      for (int h = 0; h < 2; ++h) {
        f32x4 z = {0.f, 0.f, 0.f, 0.f};
        sc[u][h] = z;
      }
#pragma unroll
    for (int h = 0; h < 2; ++h)
#pragma unroll
      for (int c = 0; c < 4; ++c) {
        s16x8 kf = *(const s16x8*)(&k_lds[cur][(size_t)((h * 4 + c) * 64 + lane) * 16]);
        sc[0][h] = __builtin_amdgcn_mfma_f32_16x16x32_bf16(kf, qf[0][c], sc[0][h], 0, 0, 0);
        sc[1][h] = __builtin_amdgcn_mfma_f32_16x16x32_bf16(kf, qf[1][c], sc[1][h], 0, 0, 0);
      }

    // ---- softmax (base-2, lane-local rows) ----
    s16x8 pf[2];
#pragma unroll
    for (int u = 0; u < 2; ++u) {
      float sv[8];
#pragma unroll
      for (int h = 0; h < 2; ++h)
#pragma unroll
        for (int r = 0; r < 4; ++r)
          sv[4 * h + r] = sc[u][h][r];
      if (t32 >= S_CACHE) {  // causal mask (uniform branch per tile)
        const int qglob = qg32 * 32 + u * 16 + qq;
#pragma unroll
        for (int nn = 0; nn < 8; ++nn) {
          const int key = t32 + 8 * g + nn;
          if (key - S_CACHE > qglob) sv[nn] = -1e30f;
        }
      }
      float vmax = fmaxf(fmaxf(fmaxf(sv[0], sv[1]), fmaxf(sv[2], sv[3])),
                         fmaxf(fmaxf(sv[4], sv[5]), fmaxf(sv[6], sv[7])));
      vmax = fmaxf(vmax, __shfl_xor(vmax, 16, 64));
      vmax = fmaxf(vmax, __shfl_xor(vmax, 32, 64));
      if (!__all(vmax <= mrun[u] + 8.f)) {  // defer-max
        const float mnew = fmaxf(mrun[u], vmax);
        const float corr = exp2f(mrun[u] - mnew);
        lrun[u] *= corr;
#pragma unroll
        for (int dt = 0; dt < 8; ++dt) oacc[u][dt] *= corr;
        mrun[u] = mnew;
      }
      float p[8], rs = 0.f;
#pragma unroll
      for (int nn = 0; nn < 8; ++nn) {
        p[nn] = exp2f(sv[nn] - mrun[u]);
        rs += p[nn];
      }
      rs += __shfl_xor(rs, 16, 64);
      rs += __shfl_xor(rs, 32, 64);
      lrun[u] += rs;
      pf[u] = frag4(cvtpk(p[0], p[1]), cvtpk(p[2], p[3]),
                    cvtpk(p[4], p[5]), cvtpk(p[6], p[7]));
    }

    // ---- PV (swapped): O^T += V^T @ P^T ----
#pragma unroll
    for (int dt = 0; dt < 8; ++dt) {
      s16x8 vf = *(const s16x8*)(&v_lds[cur][(size_t)(dt * 64 + lane) * 16]);
      oacc[0][dt] = __builtin_amdgcn_mfma_f32_16x16x32_bf16(vf, pf[0], oacc[0][dt], 0, 0, 0);
      oacc[1][dt] = __builtin_amdgcn_mfma_f32_16x16x32_bf16(vf, pf[1], oacc[1][dt], 0, 0, 0);
    }

    if (havenext) stage_write(cur ^ 1);
    cur ^= 1;
  }

  // ---- write partial: O^T [128 dv][32 q] bf16 + m[32] + l[32] f32 ----
  unsigned char* pbase = ws + (size_t)(qg32 * ksplit + s) * PARTIAL_BYTES;
  unsigned short* pO = (unsigned short*)pbase;
  float* pml = (float*)(pbase + 8192);
#pragma unroll
  for (int u = 0; u < 2; ++u) {
#pragma unroll
    for (int dt = 0; dt < 8; ++dt)
#pragma unroll
      for (int r = 0; r < 4; ++r)
        pO[(size_t)(16 * dt + 4 * g + r) * 32 + u * 16 + qq] = f2bf(oacc[u][dt][r]);
    if (g == 0) {
      pml[u * 16 + qq] = mrun[u];
      pml[32 + u * 16 + qq] = lrun[u];
    }
  }
}

// ---------------------------------------------------------------------------
// Combine: one thread per (q, dv).
// ---------------------------------------------------------------------------
__global__ __launch_bounds__(256) void mt_attn_combine(
    const unsigned char* __restrict__ ws, float* __restrict__ out, int ksplit)
{
  const int t  = blockIdx.x * 256 + threadIdx.x;  // 131072 total
  const int ql = t & 31;
  const int dv = (t >> 5) & 127;
  const int qg = t >> 12;
  const unsigned char* base = ws + (size_t)qg * ksplit * PARTIAL_BYTES;
  float mg = -1e30f;
  for (int s = 0; s < ksplit; ++s)
    mg = fmaxf(mg, *(const float*)(base + (size_t)s * PARTIAL_BYTES + 8192 + 4 * ql));
  float L = 0.f, acc = 0.f;
  for (int s = 0; s < ksplit; ++s) {
    const unsigned char* pb = base + (size_t)s * PARTIAL_BYTES;
    const float m = *(const float*)(pb + 8192 + 4 * ql);
    const float l = *(const float*)(pb + 8192 + 128 + 4 * ql);
    const float wgt = exp2f(m - mg);
    const unsigned short ob = *(const unsigned short*)(pb + 2 * ((size_t)dv * 32 + ql));
    L   += wgt * l;
    acc += wgt * bf2f(ob);
  }
  out[(size_t)(qg * 32 + ql) * D + dv] = acc / L;
}

extern "C" void kernel_launch(void* const* d_in, const int* in_sizes, int n_in,
                              void* d_out, int out_size, void* d_ws, size_t ws_size,
                              hipStream_t stream)
{
  const float* qp = (const float*)d_in[0];
  const float* kp = (const float*)d_in[1];
  const float* vp = (const float*)d_in[2];
  const float* Kc = (const float*)d_in[3];
  const float* Vc = (const float*)d_in[4];
  float* out = (float*)d_out;
  unsigned char* ws = (unsigned char*)d_ws;

  // footprint: 32 qgroups x ksplit x 8448 B
  static const int cands[] = {128, 96, 64, 48, 32, 24, 16, 8};
  int ksplit = 8;
  for (int i = 0; i < 8; ++i) {
    if ((size_t)32 * cands[i] * PARTIAL_BYTES <= ws_size) { ksplit = cands[i]; break; }
  }

  mt_attn_main<<<dim3(8 * ksplit), dim3(256), 0, stream>>>(qp, kp, vp, Kc, Vc, ws, ksplit);
  mt_attn_combine<<<dim3((NQ * D) / 256), dim3(256), 0, stream>>>(ws, out, ksplit);
}

// Round 4
// 115.167 us; speedup vs baseline: 1.8154x; 1.8154x over previous
//
#include <hip/hip_runtime.h>

#define S_CACHE 32768
#define NQ 1024
#define D 128
#define KVB 32
#define TILES_TOTAL 1056
#define PARTIAL_BYTES 8448  // 4096 bf16 O^T + 32 f32 m + 32 f32 l

typedef float f32x4 __attribute__((ext_vector_type(4)));
typedef short s16x8 __attribute__((ext_vector_type(8)));
typedef int   i32x4 __attribute__((ext_vector_type(4)));

static __device__ __forceinline__ int cvtpk(float lo, float hi) {
  int r;
  asm("v_cvt_pk_bf16_f32 %0, %1, %2" : "=v"(r) : "v"(lo), "v"(hi));
  return r;
}
static __device__ __forceinline__ s16x8 frag4(int a, int b, int c, int d) {
  i32x4 t = {a, b, c, d};
  return __builtin_bit_cast(s16x8, t);
}
static __device__ __forceinline__ unsigned short f2bf(float x) {
  unsigned int u = __float_as_uint(x);
  u += 0x7fffu + ((u >> 16) & 1u);
  return (unsigned short)(u >> 16);
}
static __device__ __forceinline__ float bf2f(unsigned short b) {
  return __uint_as_float(((unsigned int)b) << 16);
}

// ---------------------------------------------------------------------------
// Main kernel: 1D grid of 8*ksplit blocks, 256 threads = 4 waves x 32 q.
// Block decode (XCD co-location): linear block n -> XCD n%8; split
// s = (n&7) + 8*(n>>6) so all 8 q-blocks of split s run on XCD s%8 within one
// 64-block dispatch window -> each split's KV is HBM-fetched once, L2-served 8x.
// Swapped-operand flash attention (R1-proven body, 92 VGPR, 0 bank conflicts):
//   S^T = mfma(A=K, B=Q^T); O^T = mfma(A=V^T, B=P^T); softmax lane-local.
// __launch_bounds__(256,2): NO tighter bound — (256,4) caused spills (R2).
// ---------------------------------------------------------------------------
__global__ __launch_bounds__(256, 2) void mt_attn_main(
    const float* __restrict__ qp, const float* __restrict__ knew,
    const float* __restrict__ vnew, const float* __restrict__ Kc,
    const float* __restrict__ Vc, unsigned char* __restrict__ ws,
    int ksplit)
{
  __shared__ __align__(16) unsigned char k_lds[2][8192];  // 8 frags (h,c) x 64 lanes x 16B
  __shared__ __align__(16) unsigned char v_lds[2][8192];  // 8 frags (dt)  x 64 lanes x 16B

  const int tid  = threadIdx.x;
  const int lane = tid & 63;
  const int w    = tid >> 6;
  const int g    = lane >> 4;
  const int qq   = lane & 15;

  // ---- block decode: co-locate a split's 8 q-blocks on one XCD ----
  const int n    = blockIdx.x;
  const int xcd  = n & 7;
  const int qg   = (n >> 3) & 7;
  const int sidx = n >> 6;
  const int s    = xcd + 8 * sidx;          // split id, s % 8 == xcd
  const int qg32 = qg * 4 + w;              // 0..31, 32 q-rows per wave
  const int t_st = (s * TILES_TOTAL) / ksplit;
  const int t_en = ((s + 1) * TILES_TOTAL) / ksplit;
  const int tiles_pb = t_en - t_st;
  const int kbase = t_st * KVB;

  // ---- Q fragments (B-operand): lane holds Q[q][32c+8g+i], scaled ----
  const float QSCALE = 0.0883883476483184f * 1.4426950408889634f;  // 1/sqrt(128)*log2(e)
  s16x8 qf[2][4];
#pragma unroll
  for (int u = 0; u < 2; ++u) {
    const float* qrow = qp + (size_t)(qg32 * 32 + u * 16 + qq) * D + 8 * g;
#pragma unroll
    for (int c = 0; c < 4; ++c) {
      f32x4 x0 = *(const f32x4*)(qrow + 32 * c);
      f32x4 x1 = *(const f32x4*)(qrow + 32 * c + 4);
      qf[u][c] = frag4(cvtpk(x0[0] * QSCALE, x0[1] * QSCALE),
                       cvtpk(x0[2] * QSCALE, x0[3] * QSCALE),
                       cvtpk(x1[0] * QSCALE, x1[1] * QSCALE),
                       cvtpk(x1[2] * QSCALE, x1[3] * QSCALE));
    }
  }

  f32x4 oacc[2][8];
#pragma unroll
  for (int u = 0; u < 2; ++u)
#pragma unroll
    for (int dt = 0; dt < 8; ++dt) {
      f32x4 z = {0.f, 0.f, 0.f, 0.f};
      oacc[u][dt] = z;
    }
  float mrun[2] = {-1e30f, -1e30f};
  float lrun[2] = {0.f, 0.f};

  // staging geometry: K chunks (h=0/1, c=w), V chunks (dt=w, w+4)
  const int kitr = 8 * (qq >> 2) + (qq & 3);
  const int kcol = 32 * w + 8 * g;

  f32x4 ka[4];
  float va[16];

  auto stage_load = [&](int t32) {
    const float* kb_;
    const float* vb_;
    if (t32 < S_CACHE) {
      kb_ = Kc + (size_t)t32 * D;
      vb_ = Vc + (size_t)t32 * D;
    } else {
      kb_ = knew + (size_t)(t32 - S_CACHE) * D;
      vb_ = vnew + (size_t)(t32 - S_CACHE) * D;
    }
    ka[0] = *(const f32x4*)(kb_ + (size_t)kitr * D + kcol);
    ka[1] = *(const f32x4*)(kb_ + (size_t)kitr * D + kcol + 4);
    ka[2] = *(const f32x4*)(kb_ + (size_t)(kitr + 4) * D + kcol);
    ka[3] = *(const f32x4*)(kb_ + (size_t)(kitr + 4) * D + kcol + 4);
#pragma unroll
    for (int j = 0; j < 2; ++j) {
      const int dt = w + 4 * j;
#pragma unroll
      for (int i = 0; i < 8; ++i)
        va[8 * j + i] = vb_[(size_t)(8 * g + i) * D + 16 * dt + qq];
    }
  };

  auto stage_write = [&](int b) {
    i32x4 kc0 = {cvtpk(ka[0][0], ka[0][1]), cvtpk(ka[0][2], ka[0][3]),
                 cvtpk(ka[1][0], ka[1][1]), cvtpk(ka[1][2], ka[1][3])};
    *(i32x4*)(&k_lds[b][(size_t)((w)*64 + lane) * 16]) = kc0;
    i32x4 kc1 = {cvtpk(ka[2][0], ka[2][1]), cvtpk(ka[2][2], ka[2][3]),
                 cvtpk(ka[3][0], ka[3][1]), cvtpk(ka[3][2], ka[3][3])};
    *(i32x4*)(&k_lds[b][(size_t)((4 + w) * 64 + lane) * 16]) = kc1;
#pragma unroll
    for (int j = 0; j < 2; ++j) {
      i32x4 vc = {cvtpk(va[8 * j + 0], va[8 * j + 1]), cvtpk(va[8 * j + 2], va[8 * j + 3]),
                  cvtpk(va[8 * j + 4], va[8 * j + 5]), cvtpk(va[8 * j + 6], va[8 * j + 7])};
      *(i32x4*)(&v_lds[b][(size_t)((w + 4 * j) * 64 + lane) * 16]) = vc;
    }
  };

  stage_load(kbase);
  stage_write(0);
  int cur = 0;

  for (int tile = 0; tile < tiles_pb; ++tile) {
    const int t32 = kbase + tile * KVB;
    __syncthreads();

    const bool havenext = (tile + 1 < tiles_pb);
    if (havenext) stage_load(t32 + KVB);  // issue loads early; consumed in stage_write

    // ---- QK^T (swapped): lane(g,qq) gets scores for q=qq, keys 8g+n ----
    f32x4 sc[2][2];
#pragma unroll
    for (int u = 0; u < 2; ++u)
#pragma unroll
      for (int h = 0; h < 2; ++h) {
        f32x4 z = {0.f, 0.f, 0.f, 0.f};
        sc[u][h] = z;
      }
#pragma unroll
    for (int h = 0; h < 2; ++h)
#pragma unroll
      for (int c = 0; c < 4; ++c) {
        s16x8 kf = *(const s16x8*)(&k_lds[cur][(size_t)((h * 4 + c) * 64 + lane) * 16]);
        sc[0][h] = __builtin_amdgcn_mfma_f32_16x16x32_bf16(kf, qf[0][c], sc[0][h], 0, 0, 0);
        sc[1][h] = __builtin_amdgcn_mfma_f32_16x16x32_bf16(kf, qf[1][c], sc[1][h], 0, 0, 0);
      }

    // ---- softmax (base-2, lane-local rows) ----
    s16x8 pf[2];
#pragma unroll
    for (int u = 0; u < 2; ++u) {
      float sv[8];
#pragma unroll
      for (int h = 0; h < 2; ++h)
#pragma unroll
        for (int r = 0; r < 4; ++r)
          sv[4 * h + r] = sc[u][h][r];
      if (t32 >= S_CACHE) {  // causal mask (uniform branch per tile)
        const int qglob = qg32 * 32 + u * 16 + qq;
#pragma unroll
        for (int nn = 0; nn < 8; ++nn) {
          const int key = t32 + 8 * g + nn;
          if (key - S_CACHE > qglob) sv[nn] = -1e30f;
        }
      }
      float vmax = fmaxf(fmaxf(fmaxf(sv[0], sv[1]), fmaxf(sv[2], sv[3])),
                         fmaxf(fmaxf(sv[4], sv[5]), fmaxf(sv[6], sv[7])));
      vmax = fmaxf(vmax, __shfl_xor(vmax, 16, 64));
      vmax = fmaxf(vmax, __shfl_xor(vmax, 32, 64));
      if (!__all(vmax <= mrun[u] + 8.f)) {  // defer-max
        const float mnew = fmaxf(mrun[u], vmax);
        const float corr = exp2f(mrun[u] - mnew);
        lrun[u] *= corr;
#pragma unroll
        for (int dt = 0; dt < 8; ++dt) oacc[u][dt] *= corr;
        mrun[u] = mnew;
      }
      float p[8], rs = 0.f;
#pragma unroll
      for (int nn = 0; nn < 8; ++nn) {
        p[nn] = exp2f(sv[nn] - mrun[u]);
        rs += p[nn];
      }
      rs += __shfl_xor(rs, 16, 64);
      rs += __shfl_xor(rs, 32, 64);
      lrun[u] += rs;
      pf[u] = frag4(cvtpk(p[0], p[1]), cvtpk(p[2], p[3]),
                    cvtpk(p[4], p[5]), cvtpk(p[6], p[7]));
    }

    // ---- PV (swapped): O^T += V^T @ P^T ----
#pragma unroll
    for (int dt = 0; dt < 8; ++dt) {
      s16x8 vf = *(const s16x8*)(&v_lds[cur][(size_t)(dt * 64 + lane) * 16]);
      oacc[0][dt] = __builtin_amdgcn_mfma_f32_16x16x32_bf16(vf, pf[0], oacc[0][dt], 0, 0, 0);
      oacc[1][dt] = __builtin_amdgcn_mfma_f32_16x16x32_bf16(vf, pf[1], oacc[1][dt], 0, 0, 0);
    }

    if (havenext) stage_write(cur ^ 1);
    cur ^= 1;
  }

  // ---- write partial: O^T [128 dv][32 q] bf16 + m[32] + l[32] f32 ----
  unsigned char* pbase = ws + (size_t)(qg32 * ksplit + s) * PARTIAL_BYTES;
  unsigned short* pO = (unsigned short*)pbase;
  float* pml = (float*)(pbase + 8192);
#pragma unroll
  for (int u = 0; u < 2; ++u) {
#pragma unroll
    for (int dt = 0; dt < 8; ++dt)
#pragma unroll
      for (int r = 0; r < 4; ++r)
        pO[(size_t)(16 * dt + 4 * g + r) * 32 + u * 16 + qq] = f2bf(oacc[u][dt][r]);
    if (g == 0) {
      pml[u * 16 + qq] = mrun[u];
      pml[32 + u * 16 + qq] = lrun[u];
    }
  }
}

// ---------------------------------------------------------------------------
// Combine: one thread per (q, dv).
// ---------------------------------------------------------------------------
__global__ __launch_bounds__(256) void mt_attn_combine(
    const unsigned char* __restrict__ ws, float* __restrict__ out, int ksplit)
{
  const int t  = blockIdx.x * 256 + threadIdx.x;  // 131072 total
  const int ql = t & 31;
  const int dv = (t >> 5) & 127;
  const int qg = t >> 12;
  const unsigned char* base = ws + (size_t)qg * ksplit * PARTIAL_BYTES;
  float mg = -1e30f;
  for (int s = 0; s < ksplit; ++s)
    mg = fmaxf(mg, *(const float*)(base + (size_t)s * PARTIAL_BYTES + 8192 + 4 * ql));
  float L = 0.f, acc = 0.f;
  for (int s = 0; s < ksplit; ++s) {
    const unsigned char* pb = base + (size_t)s * PARTIAL_BYTES;
    const float m = *(const float*)(pb + 8192 + 4 * ql);
    const float l = *(const float*)(pb + 8192 + 128 + 4 * ql);
    const float wgt = exp2f(m - mg);
    const unsigned short ob = *(const unsigned short*)(pb + 2 * ((size_t)dv * 32 + ql));
    L   += wgt * l;
    acc += wgt * bf2f(ob);
  }
  out[(size_t)(qg * 32 + ql) * D + dv] = acc / L;
}

extern "C" void kernel_launch(void* const* d_in, const int* in_sizes, int n_in,
                              void* d_out, int out_size, void* d_ws, size_t ws_size,
                              hipStream_t stream)
{
  const float* qp = (const float*)d_in[0];
  const float* kp = (const float*)d_in[1];
  const float* vp = (const float*)d_in[2];
  const float* Kc = (const float*)d_in[3];
  const float* Vc = (const float*)d_in[4];
  float* out = (float*)d_out;
  unsigned char* ws = (unsigned char*)d_ws;

  // footprint: 32 qgroups x ksplit x 8448 B; all cands are multiples of 8 so
  // the XCD decode (n = 64*sidx + 8*qg + xcd) is a clean bijection.
  static const int cands[] = {128, 96, 64, 48, 32, 16, 8};
  int ksplit = 8;
  for (int i = 0; i < 7; ++i) {
    if ((size_t)32 * cands[i] * PARTIAL_BYTES <= ws_size) { ksplit = cands[i]; break; }
  }

  mt_attn_main<<<dim3(8 * ksplit), dim3(256), 0, stream>>>(qp, kp, vp, Kc, Vc, ws, ksplit);
  mt_attn_combine<<<dim3((NQ * D) / 256), dim3(256), 0, stream>>>(ws, out, ksplit);
}

// Round 5
// 73.315 us; speedup vs baseline: 2.8517x; 1.5708x over previous
//
#include <hip/hip_runtime.h>

#define S_CACHE 32768
#define NQ 1024
#define D 128
#define KVB 32
#define TILES_TOTAL 1056
#define OBLK_BYTES 8192  // per (qg32, split): O^T [128 dv][32 q] bf16

typedef float f32x4 __attribute__((ext_vector_type(4)));
typedef short s16x8 __attribute__((ext_vector_type(8)));
typedef int   i32x4 __attribute__((ext_vector_type(4)));

static __device__ __forceinline__ int cvtpk(float lo, float hi) {
  int r;
  asm("v_cvt_pk_bf16_f32 %0, %1, %2" : "=v"(r) : "v"(lo), "v"(hi));
  return r;
}
static __device__ __forceinline__ s16x8 frag4(int a, int b, int c, int d) {
  i32x4 t = {a, b, c, d};
  return __builtin_bit_cast(s16x8, t);
}
static __device__ __forceinline__ unsigned short f2bf(float x) {
  unsigned int u = __float_as_uint(x);
  u += 0x7fffu + ((u >> 16) & 1u);
  return (unsigned short)(u >> 16);
}
static __device__ __forceinline__ float bf2f(unsigned short b) {
  return __uint_as_float(((unsigned int)b) << 16);
}

// ---------------------------------------------------------------------------
// Main kernel: 1D grid of 8*ksplit blocks, 256 threads = 4 waves x 32 q.
// Block decode (XCD co-location): linear block n -> XCD n%8; split
// s = (n&7) + 8*(n>>6) so all 8 q-blocks of split s run on XCD s%8 within one
// 64-block dispatch window -> each split's KV is HBM-fetched once, L2-served 8x.
// Swapped-operand flash attention (92 VGPR, 0 bank conflicts):
//   S^T = mfma(A=K, B=Q^T); O^T = mfma(A=V^T, B=P^T); softmax lane-local.
// __launch_bounds__(256,2): NO tighter bound — (256,4) caused spills (R2).
// ---------------------------------------------------------------------------
__global__ __launch_bounds__(256, 2) void mt_attn_main(
    const float* __restrict__ qp, const float* __restrict__ knew,
    const float* __restrict__ vnew, const float* __restrict__ Kc,
    const float* __restrict__ Vc, unsigned char* __restrict__ ws,
    int ksplit)
{
  __shared__ __align__(16) unsigned char k_lds[2][8192];  // 8 frags (h,c) x 64 lanes x 16B
  __shared__ __align__(16) unsigned char v_lds[2][8192];  // 8 frags (dt)  x 64 lanes x 16B

  const int tid  = threadIdx.x;
  const int lane = tid & 63;
  const int w    = tid >> 6;
  const int g    = lane >> 4;
  const int qq   = lane & 15;

  // ---- block decode: co-locate a split's 8 q-blocks on one XCD ----
  const int n    = blockIdx.x;
  const int xcd  = n & 7;
  const int qg   = (n >> 3) & 7;
  const int sidx = n >> 6;
  const int s    = xcd + 8 * sidx;          // split id, s % 8 == xcd
  const int qg32 = qg * 4 + w;              // 0..31, 32 q-rows per wave
  const int t_st = (s * TILES_TOTAL) / ksplit;
  const int t_en = ((s + 1) * TILES_TOTAL) / ksplit;
  const int tiles_pb = t_en - t_st;
  const int kbase = t_st * KVB;

  // staging geometry: K chunks (h=0/1, c=w), V chunks (dt=w, w+4)
  const int kitr = 8 * (qq >> 2) + (qq & 3);
  const int kcol = 32 * w + 8 * g;

  f32x4 ka[4];
  float va[16];

  auto stage_load = [&](int t32) {
    const float* kb_;
    const float* vb_;
    if (t32 < S_CACHE) {
      kb_ = Kc + (size_t)t32 * D;
      vb_ = Vc + (size_t)t32 * D;
    } else {
      kb_ = knew + (size_t)(t32 - S_CACHE) * D;
      vb_ = vnew + (size_t)(t32 - S_CACHE) * D;
    }
    ka[0] = *(const f32x4*)(kb_ + (size_t)kitr * D + kcol);
    ka[1] = *(const f32x4*)(kb_ + (size_t)kitr * D + kcol + 4);
    ka[2] = *(const f32x4*)(kb_ + (size_t)(kitr + 4) * D + kcol);
    ka[3] = *(const f32x4*)(kb_ + (size_t)(kitr + 4) * D + kcol + 4);
#pragma unroll
    for (int j = 0; j < 2; ++j) {
      const int dt = w + 4 * j;
#pragma unroll
      for (int i = 0; i < 8; ++i)
        va[8 * j + i] = vb_[(size_t)(8 * g + i) * D + 16 * dt + qq];
    }
  };

  auto stage_write = [&](int b) {
    i32x4 kc0 = {cvtpk(ka[0][0], ka[0][1]), cvtpk(ka[0][2], ka[0][3]),
                 cvtpk(ka[1][0], ka[1][1]), cvtpk(ka[1][2], ka[1][3])};
    *(i32x4*)(&k_lds[b][(size_t)((w)*64 + lane) * 16]) = kc0;
    i32x4 kc1 = {cvtpk(ka[2][0], ka[2][1]), cvtpk(ka[2][2], ka[2][3]),
                 cvtpk(ka[3][0], ka[3][1]), cvtpk(ka[3][2], ka[3][3])};
    *(i32x4*)(&k_lds[b][(size_t)((4 + w) * 64 + lane) * 16]) = kc1;
#pragma unroll
    for (int j = 0; j < 2; ++j) {
      i32x4 vc = {cvtpk(va[8 * j + 0], va[8 * j + 1]), cvtpk(va[8 * j + 2], va[8 * j + 3]),
                  cvtpk(va[8 * j + 4], va[8 * j + 5]), cvtpk(va[8 * j + 6], va[8 * j + 7])};
      *(i32x4*)(&v_lds[b][(size_t)((w + 4 * j) * 64 + lane) * 16]) = vc;
    }
  };

  // issue first KV stage loads BEFORE Q-frag build: Q latency overlaps staging
  stage_load(kbase);

  // ---- Q fragments (B-operand): lane holds Q[q][32c+8g+i], scaled ----
  const float QSCALE = 0.0883883476483184f * 1.4426950408889634f;  // 1/sqrt(128)*log2(e)
  s16x8 qf[2][4];
#pragma unroll
  for (int u = 0; u < 2; ++u) {
    const float* qrow = qp + (size_t)(qg32 * 32 + u * 16 + qq) * D + 8 * g;
#pragma unroll
    for (int c = 0; c < 4; ++c) {
      f32x4 x0 = *(const f32x4*)(qrow + 32 * c);
      f32x4 x1 = *(const f32x4*)(qrow + 32 * c + 4);
      qf[u][c] = frag4(cvtpk(x0[0] * QSCALE, x0[1] * QSCALE),
                       cvtpk(x0[2] * QSCALE, x0[3] * QSCALE),
                       cvtpk(x1[0] * QSCALE, x1[1] * QSCALE),
                       cvtpk(x1[2] * QSCALE, x1[3] * QSCALE));
    }
  }

  f32x4 oacc[2][8];
#pragma unroll
  for (int u = 0; u < 2; ++u)
#pragma unroll
    for (int dt = 0; dt < 8; ++dt) {
      f32x4 z = {0.f, 0.f, 0.f, 0.f};
      oacc[u][dt] = z;
    }
  float mrun[2] = {-1e30f, -1e30f};
  float lrun[2] = {0.f, 0.f};

  stage_write(0);
  int cur = 0;

  for (int tile = 0; tile < tiles_pb; ++tile) {
    const int t32 = kbase + tile * KVB;
    __syncthreads();

    const bool havenext = (tile + 1 < tiles_pb);
    if (havenext) stage_load(t32 + KVB);  // issue loads early; consumed in stage_write

    // ---- QK^T (swapped): lane(g,qq) gets scores for q=qq, keys 8g+n ----
    f32x4 sc[2][2];
#pragma unroll
    for (int u = 0; u < 2; ++u)
#pragma unroll
      for (int h = 0; h < 2; ++h) {
        f32x4 z = {0.f, 0.f, 0.f, 0.f};
        sc[u][h] = z;
      }
#pragma unroll
    for (int h = 0; h < 2; ++h)
#pragma unroll
      for (int c = 0; c < 4; ++c) {
        s16x8 kf = *(const s16x8*)(&k_lds[cur][(size_t)((h * 4 + c) * 64 + lane) * 16]);
        sc[0][h] = __builtin_amdgcn_mfma_f32_16x16x32_bf16(kf, qf[0][c], sc[0][h], 0, 0, 0);
        sc[1][h] = __builtin_amdgcn_mfma_f32_16x16x32_bf16(kf, qf[1][c], sc[1][h], 0, 0, 0);
      }

    // ---- softmax (base-2, lane-local rows) ----
    s16x8 pf[2];
#pragma unroll
    for (int u = 0; u < 2; ++u) {
      float sv[8];
#pragma unroll
      for (int h = 0; h < 2; ++h)
#pragma unroll
        for (int r = 0; r < 4; ++r)
          sv[4 * h + r] = sc[u][h][r];
      if (t32 >= S_CACHE) {  // causal mask (uniform branch per tile)
        const int qglob = qg32 * 32 + u * 16 + qq;
#pragma unroll
        for (int nn = 0; nn < 8; ++nn) {
          const int key = t32 + 8 * g + nn;
          if (key - S_CACHE > qglob) sv[nn] = -1e30f;
        }
      }
      float vmax = fmaxf(fmaxf(fmaxf(sv[0], sv[1]), fmaxf(sv[2], sv[3])),
                         fmaxf(fmaxf(sv[4], sv[5]), fmaxf(sv[6], sv[7])));
      vmax = fmaxf(vmax, __shfl_xor(vmax, 16, 64));
      vmax = fmaxf(vmax, __shfl_xor(vmax, 32, 64));
      if (!__all(vmax <= mrun[u] + 8.f)) {  // defer-max
        const float mnew = fmaxf(mrun[u], vmax);
        const float corr = exp2f(mrun[u] - mnew);
        lrun[u] *= corr;
#pragma unroll
        for (int dt = 0; dt < 8; ++dt) oacc[u][dt] *= corr;
        mrun[u] = mnew;
      }
      float p[8], rs = 0.f;
#pragma unroll
      for (int nn = 0; nn < 8; ++nn) {
        p[nn] = exp2f(sv[nn] - mrun[u]);
        rs += p[nn];
      }
      rs += __shfl_xor(rs, 16, 64);
      rs += __shfl_xor(rs, 32, 64);
      lrun[u] += rs;
      pf[u] = frag4(cvtpk(p[0], p[1]), cvtpk(p[2], p[3]),
                    cvtpk(p[4], p[5]), cvtpk(p[6], p[7]));
    }

    // ---- PV (swapped): O^T += V^T @ P^T ----
#pragma unroll
    for (int dt = 0; dt < 8; ++dt) {
      s16x8 vf = *(const s16x8*)(&v_lds[cur][(size_t)(dt * 64 + lane) * 16]);
      oacc[0][dt] = __builtin_amdgcn_mfma_f32_16x16x32_bf16(vf, pf[0], oacc[0][dt], 0, 0, 0);
      oacc[1][dt] = __builtin_amdgcn_mfma_f32_16x16x32_bf16(vf, pf[1], oacc[1][dt], 0, 0, 0);
    }

    if (havenext) stage_write(cur ^ 1);
    cur ^= 1;
  }

  // ---- write partials: O^T [128 dv][32 q] bf16; m,l to dense [q][split] ----
  unsigned short* pO = (unsigned short*)(ws + (size_t)(qg32 * ksplit + s) * OBLK_BYTES);
  float* m_ws = (float*)(ws + (size_t)32 * ksplit * OBLK_BYTES);
  float* l_ws = m_ws + (size_t)NQ * ksplit;
#pragma unroll
  for (int u = 0; u < 2; ++u) {
#pragma unroll
    for (int dt = 0; dt < 8; ++dt)
#pragma unroll
      for (int r = 0; r < 4; ++r)
        pO[(size_t)(16 * dt + 4 * g + r) * 32 + u * 16 + qq] = f2bf(oacc[u][dt][r]);
    if (g == 0) {
      const int q = qg32 * 32 + u * 16 + qq;
      m_ws[(size_t)q * ksplit + s] = mrun[u];
      l_ws[(size_t)q * ksplit + s] = lrun[u];
    }
  }
}

// ---------------------------------------------------------------------------
// Combine, templated on SPLITS for full unroll (batched loads, MLP-hidden).
// One thread per (q, dv). m/l rows are dense in s -> f32x4 loads.
// ---------------------------------------------------------------------------
template <int S>
__global__ __launch_bounds__(256) void mt_attn_combine(
    const unsigned char* __restrict__ ws, float* __restrict__ out)
{
  const int t  = blockIdx.x * 256 + threadIdx.x;  // 131072 total
  const int ql = t & 31;
  const int dv = (t >> 5) & 127;
  const int qg = t >> 12;
  const int q  = qg * 32 + ql;

  const float* m_ws = (const float*)(ws + (size_t)32 * S * OBLK_BYTES);
  const float* l_ws = m_ws + (size_t)NQ * S;
  const float* mrow = m_ws + (size_t)q * S;
  const float* lrow = l_ws + (size_t)q * S;

  // pass 1: global max (vectorized, fully unrolled)
  float mg = -1e30f;
#pragma unroll
  for (int s4 = 0; s4 < S / 4; ++s4) {
    f32x4 m4 = *(const f32x4*)(mrow + 4 * s4);
    mg = fmaxf(mg, fmaxf(fmaxf(m4[0], m4[1]), fmaxf(m4[2], m4[3])));
  }
  // pass 2: L = sum l_s * 2^(m_s - mg)
  float L = 0.f;
#pragma unroll
  for (int s4 = 0; s4 < S / 4; ++s4) {
    f32x4 m4 = *(const f32x4*)(mrow + 4 * s4);
    f32x4 l4 = *(const f32x4*)(lrow + 4 * s4);
    L += l4[0] * exp2f(m4[0] - mg) + l4[1] * exp2f(m4[1] - mg) +
         l4[2] * exp2f(m4[2] - mg) + l4[3] * exp2f(m4[3] - mg);
  }
  // pass 3: O (fully unrolled -> loads batched; m re-reads are L1-hot)
  const unsigned char* base = ws + (size_t)qg * S * OBLK_BYTES;
  float acc = 0.f;
#pragma unroll
  for (int s = 0; s < S; ++s) {
    const float wgt = exp2f(mrow[s] - mg);
    const unsigned short ob =
        *(const unsigned short*)(base + (size_t)s * OBLK_BYTES + 2 * (dv * 32 + ql));
    acc += wgt * bf2f(ob);
  }
  out[(size_t)q * D + dv] = acc / L;
}

extern "C" void kernel_launch(void* const* d_in, const int* in_sizes, int n_in,
                              void* d_out, int out_size, void* d_ws, size_t ws_size,
                              hipStream_t stream)
{
  const float* qp = (const float*)d_in[0];
  const float* kp = (const float*)d_in[1];
  const float* vp = (const float*)d_in[2];
  const float* Kc = (const float*)d_in[3];
  const float* Vc = (const float*)d_in[4];
  float* out = (float*)d_out;
  unsigned char* ws = (unsigned char*)d_ws;

  // footprint: 32*S*8192 (O) + 2*1024*S*4 (m,l); S multiple of 8 for XCD decode
  static const int cands[] = {128, 64, 32, 16, 8};
  int ksplit = 8;
  for (int i = 0; i < 5; ++i) {
    size_t need = (size_t)32 * cands[i] * OBLK_BYTES + (size_t)2 * NQ * cands[i] * 4;
    if (need <= ws_size) { ksplit = cands[i]; break; }
  }

  mt_attn_main<<<dim3(8 * ksplit), dim3(256), 0, stream>>>(qp, kp, vp, Kc, Vc, ws, ksplit);

  const dim3 cgrid((NQ * D) / 256), cblk(256);
  switch (ksplit) {
    case 128: mt_attn_combine<128><<<cgrid, cblk, 0, stream>>>(ws, out); break;
    case 64:  mt_attn_combine<64><<<cgrid, cblk, 0, stream>>>(ws, out); break;
    case 32:  mt_attn_combine<32><<<cgrid, cblk, 0, stream>>>(ws, out); break;
    case 16:  mt_attn_combine<16><<<cgrid, cblk, 0, stream>>>(ws, out); break;
    default:  mt_attn_combine<8><<<cgrid, cblk, 0, stream>>>(ws, out); break;
  }
}

// Round 6
// 70.430 us; speedup vs baseline: 2.9685x; 1.0410x over previous
//
#include <hip/hip_runtime.h>

#define S_CACHE 32768
#define NQ 1024
#define D 128
#define KVB 32
#define TILES_TOTAL 1056
#define OBLK_BYTES 8192     // per (qg32, split): O^T [128 dv][32 q] bf16
#define KV_TILE_BYTES 16384 // prepacked K frags (8 KB) + V frags (8 KB)
#define KV_BYTES ((size_t)TILES_TOTAL * KV_TILE_BYTES)  // 17,301,504

typedef float f32x4 __attribute__((ext_vector_type(4)));
typedef short s16x8 __attribute__((ext_vector_type(8)));
typedef int   i32x4 __attribute__((ext_vector_type(4)));

static __device__ __forceinline__ int cvtpk(float lo, float hi) {
  int r;
  asm("v_cvt_pk_bf16_f32 %0, %1, %2" : "=v"(r) : "v"(lo), "v"(hi));
  return r;
}
static __device__ __forceinline__ s16x8 frag4(int a, int b, int c, int d) {
  i32x4 t = {a, b, c, d};
  return __builtin_bit_cast(s16x8, t);
}
static __device__ __forceinline__ unsigned short f2bf(float x) {
  unsigned int u = __float_as_uint(x);
  u += 0x7fffu + ((u >> 16) & 1u);
  return (unsigned short)(u >> 16);
}
static __device__ __forceinline__ float bf2f(unsigned short b) {
  return __uint_as_float(((unsigned int)b) << 16);
}
// async global->LDS, 16B per lane; lds dest must be wave-uniform base
static __device__ __forceinline__ void llds16(const unsigned char* g, unsigned char* l) {
  __builtin_amdgcn_global_load_lds(
      (const __attribute__((address_space(1))) unsigned int*)g,
      (__attribute__((address_space(3))) unsigned int*)l, 16, 0, 0);
}

// ---------------------------------------------------------------------------
// Prepack: K/V f32 -> bf16 in the exact MFMA-fragment LDS image order.
// Tile t image (16 KB): bytes [0,8K): K chunk fc=(h*4+c), lane l=(g,qq):
//   K[t*32 + 8*(qq>>2)+(qq&3)+4h][32c+8g .. +7]   (8 bf16)
// bytes [8K,16K): V chunk dt, lane (g,qq): V[t*32+8g+i][16dt+qq], i=0..7.
// One block per tile; 1024 chunk-lane jobs / 256 threads = 4 reps.
// ---------------------------------------------------------------------------
__global__ __launch_bounds__(256) void mt_prepack(
    const float* __restrict__ Kc, const float* __restrict__ Vc,
    const float* __restrict__ knew, const float* __restrict__ vnew,
    unsigned char* __restrict__ kv)
{
  const int t = blockIdx.x;
  const int t32 = t * KVB;
  const float* Kb = (t32 < S_CACHE) ? Kc + (size_t)t32 * D
                                    : knew + (size_t)(t32 - S_CACHE) * D;
  const float* Vb = (t32 < S_CACHE) ? Vc + (size_t)t32 * D
                                    : vnew + (size_t)(t32 - S_CACHE) * D;
  unsigned char* outb = kv + (size_t)t * KV_TILE_BYTES;
#pragma unroll
  for (int rep = 0; rep < 4; ++rep) {
    const int id = rep * 256 + threadIdx.x;
    const int chunk = id >> 6;   // uniform per wave
    const int l  = id & 63;
    const int g  = l >> 4, qq = l & 15;
    i32x4 outv;
    if (chunk < 8) {
      const int h = chunk >> 2, c = chunk & 3;
      const int krow = 8 * (qq >> 2) + (qq & 3) + 4 * h;
      const float* src = Kb + (size_t)krow * D + 32 * c + 8 * g;
      f32x4 x0 = *(const f32x4*)src;
      f32x4 x1 = *(const f32x4*)(src + 4);
      outv = i32x4{cvtpk(x0[0], x0[1]), cvtpk(x0[2], x0[3]),
                   cvtpk(x1[0], x1[1]), cvtpk(x1[2], x1[3])};
    } else {
      const int dt = chunk - 8;
      float v[8];
#pragma unroll
      for (int i = 0; i < 8; ++i)
        v[i] = Vb[(size_t)(8 * g + i) * D + 16 * dt + qq];
      outv = i32x4{cvtpk(v[0], v[1]), cvtpk(v[2], v[3]),
                   cvtpk(v[4], v[5]), cvtpk(v[6], v[7])};
    }
    *(i32x4*)(outb + (size_t)chunk * 1024 + l * 16) = outv;
  }
}

// ---------------------------------------------------------------------------
// Main: 1D grid of 8*ksplit blocks, 256 threads = 4 waves x 32 q.
// XCD co-location decode: split s = (n&7)+8*(n>>6) -> its 8 q-blocks share
// one XCD's L2 within a 64-block window (R4: FETCH 135->20 MB).
// Staging = 4x global_load_lds_dwordx4 per thread per tile from prepacked kv
// (zero VALU, linear LDS dest). Double-buffered, m97 barrier pattern.
// Swapped-operand flash attention, softmax lane-local, defer-max.
// ---------------------------------------------------------------------------
__global__ __launch_bounds__(256, 2) void mt_attn_main(
    const float* __restrict__ qp, const unsigned char* __restrict__ kv,
    unsigned char* __restrict__ ws, int ksplit)
{
  __shared__ __align__(16) unsigned char lds[2][KV_TILE_BYTES];

  const int tid  = threadIdx.x;
  const int lane = tid & 63;
  const int w    = tid >> 6;
  const int g    = lane >> 4;
  const int qq   = lane & 15;

  const int n    = blockIdx.x;
  const int xcd  = n & 7;
  const int qg   = (n >> 3) & 7;
  const int sidx = n >> 6;
  const int s    = xcd + 8 * sidx;
  const int qg32 = qg * 4 + w;
  const int t_st = (s * TILES_TOTAL) / ksplit;
  const int t_en = ((s + 1) * TILES_TOTAL) / ksplit;
  const int tiles_pb = t_en - t_st;

  auto stage_issue = [&](int t, int b) {
    const unsigned char* src = kv + (size_t)t * KV_TILE_BYTES + w * 1024 + lane * 16;
    unsigned char* dst = &lds[b][w * 1024];
#pragma unroll
    for (int r = 0; r < 4; ++r)
      llds16(src + r * 4096, dst + r * 4096);
  };

  stage_issue(t_st, 0);  // tile-0 loads in flight under Q-frag build

  // ---- Q fragments (B-operand): lane holds Q[q][32c+8g+i], scaled ----
  const float QSCALE = 0.0883883476483184f * 1.4426950408889634f;  // 1/sqrt(128)*log2(e)
  s16x8 qf[2][4];
#pragma unroll
  for (int u = 0; u < 2; ++u) {
    const float* qrow = qp + (size_t)(qg32 * 32 + u * 16 + qq) * D + 8 * g;
#pragma unroll
    for (int c = 0; c < 4; ++c) {
      f32x4 x0 = *(const f32x4*)(qrow + 32 * c);
      f32x4 x1 = *(const f32x4*)(qrow + 32 * c + 4);
      qf[u][c] = frag4(cvtpk(x0[0] * QSCALE, x0[1] * QSCALE),
                       cvtpk(x0[2] * QSCALE, x0[3] * QSCALE),
                       cvtpk(x1[0] * QSCALE, x1[1] * QSCALE),
                       cvtpk(x1[2] * QSCALE, x1[3] * QSCALE));
    }
  }

  f32x4 oacc[2][8];
#pragma unroll
  for (int u = 0; u < 2; ++u)
#pragma unroll
    for (int dt = 0; dt < 8; ++dt) {
      f32x4 z = {0.f, 0.f, 0.f, 0.f};
      oacc[u][dt] = z;
    }
  float mrun[2] = {-1e30f, -1e30f};
  float lrun[2] = {0.f, 0.f};

  int cur = 0;
  for (int tile = 0; tile < tiles_pb; ++tile) {
    const int t32 = (t_st + tile) * KVB;
    __syncthreads();  // drains vmcnt -> lds[cur] ready; prev-buf reads done

    if (tile + 1 < tiles_pb) stage_issue(t_st + tile + 1, cur ^ 1);

    // ---- QK^T (swapped): lane(g,qq) gets scores for q=qq, keys 8g+n ----
    f32x4 sc[2][2];
#pragma unroll
    for (int u = 0; u < 2; ++u)
#pragma unroll
      for (int h = 0; h < 2; ++h) {
        f32x4 z = {0.f, 0.f, 0.f, 0.f};
        sc[u][h] = z;
      }
#pragma unroll
    for (int h = 0; h < 2; ++h)
#pragma unroll
      for (int c = 0; c < 4; ++c) {
        s16x8 kf = *(const s16x8*)(&lds[cur][(size_t)((h * 4 + c) * 64 + lane) * 16]);
        sc[0][h] = __builtin_amdgcn_mfma_f32_16x16x32_bf16(kf, qf[0][c], sc[0][h], 0, 0, 0);
        sc[1][h] = __builtin_amdgcn_mfma_f32_16x16x32_bf16(kf, qf[1][c], sc[1][h], 0, 0, 0);
      }

    // ---- softmax (base-2, lane-local rows) ----
    s16x8 pf[2];
#pragma unroll
    for (int u = 0; u < 2; ++u) {
      float sv[8];
#pragma unroll
      for (int h = 0; h < 2; ++h)
#pragma unroll
        for (int r = 0; r < 4; ++r)
          sv[4 * h + r] = sc[u][h][r];
      if (t32 >= S_CACHE) {  // causal mask (uniform branch per tile)
        const int qglob = qg32 * 32 + u * 16 + qq;
#pragma unroll
        for (int nn = 0; nn < 8; ++nn) {
          const int key = t32 + 8 * g + nn;
          if (key - S_CACHE > qglob) sv[nn] = -1e30f;
        }
      }
      float vmax = fmaxf(fmaxf(fmaxf(sv[0], sv[1]), fmaxf(sv[2], sv[3])),
                         fmaxf(fmaxf(sv[4], sv[5]), fmaxf(sv[6], sv[7])));
      vmax = fmaxf(vmax, __shfl_xor(vmax, 16, 64));
      vmax = fmaxf(vmax, __shfl_xor(vmax, 32, 64));
      if (!__all(vmax <= mrun[u] + 8.f)) {  // defer-max
        const float mnew = fmaxf(mrun[u], vmax);
        const float corr = exp2f(mrun[u] - mnew);
        lrun[u] *= corr;
#pragma unroll
        for (int dt = 0; dt < 8; ++dt) oacc[u][dt] *= corr;
        mrun[u] = mnew;
      }
      float p[8], rs = 0.f;
#pragma unroll
      for (int nn = 0; nn < 8; ++nn) {
        p[nn] = exp2f(sv[nn] - mrun[u]);
        rs += p[nn];
      }
      rs += __shfl_xor(rs, 16, 64);
      rs += __shfl_xor(rs, 32, 64);
      lrun[u] += rs;
      pf[u] = frag4(cvtpk(p[0], p[1]), cvtpk(p[2], p[3]),
                    cvtpk(p[4], p[5]), cvtpk(p[6], p[7]));
    }

    // ---- PV (swapped): O^T += V^T @ P^T ----
#pragma unroll
    for (int dt = 0; dt < 8; ++dt) {
      s16x8 vf = *(const s16x8*)(&lds[cur][(size_t)(8192 + (dt * 64 + lane) * 16)]);
      oacc[0][dt] = __builtin_amdgcn_mfma_f32_16x16x32_bf16(vf, pf[0], oacc[0][dt], 0, 0, 0);
      oacc[1][dt] = __builtin_amdgcn_mfma_f32_16x16x32_bf16(vf, pf[1], oacc[1][dt], 0, 0, 0);
    }
    cur ^= 1;
  }

  // ---- write partials: O^T [128 dv][32 q] bf16; m,l dense [q][split] ----
  unsigned char* wsp = ws + KV_BYTES;
  unsigned short* pO = (unsigned short*)(wsp + (size_t)(qg32 * ksplit + s) * OBLK_BYTES);
  float* m_ws = (float*)(wsp + (size_t)32 * ksplit * OBLK_BYTES);
  float* l_ws = m_ws + (size_t)NQ * ksplit;
#pragma unroll
  for (int u = 0; u < 2; ++u) {
#pragma unroll
    for (int dt = 0; dt < 8; ++dt)
#pragma unroll
      for (int r = 0; r < 4; ++r)
        pO[(size_t)(16 * dt + 4 * g + r) * 32 + u * 16 + qq] = f2bf(oacc[u][dt][r]);
    if (g == 0) {
      const int q = qg32 * 32 + u * 16 + qq;
      m_ws[(size_t)q * ksplit + s] = mrun[u];
      l_ws[(size_t)q * ksplit + s] = lrun[u];
    }
  }
}

// ---------------------------------------------------------------------------
// Combine, templated on SPLITS for full unroll (batched loads).
// ---------------------------------------------------------------------------
template <int S>
__global__ __launch_bounds__(256) void mt_attn_combine(
    const unsigned char* __restrict__ ws, float* __restrict__ out)
{
  const int t  = blockIdx.x * 256 + threadIdx.x;  // 131072 total
  const int ql = t & 31;
  const int dv = (t >> 5) & 127;
  const int qg = t >> 12;
  const int q  = qg * 32 + ql;

  const unsigned char* wsp = ws + KV_BYTES;
  const float* m_ws = (const float*)(wsp + (size_t)32 * S * OBLK_BYTES);
  const float* l_ws = m_ws + (size_t)NQ * S;
  const float* mrow = m_ws + (size_t)q * S;
  const float* lrow = l_ws + (size_t)q * S;

  float mg = -1e30f;
#pragma unroll
  for (int s4 = 0; s4 < S / 4; ++s4) {
    f32x4 m4 = *(const f32x4*)(mrow + 4 * s4);
    mg = fmaxf(mg, fmaxf(fmaxf(m4[0], m4[1]), fmaxf(m4[2], m4[3])));
  }
  float L = 0.f;
#pragma unroll
  for (int s4 = 0; s4 < S / 4; ++s4) {
    f32x4 m4 = *(const f32x4*)(mrow + 4 * s4);
    f32x4 l4 = *(const f32x4*)(lrow + 4 * s4);
    L += l4[0] * exp2f(m4[0] - mg) + l4[1] * exp2f(m4[1] - mg) +
         l4[2] * exp2f(m4[2] - mg) + l4[3] * exp2f(m4[3] - mg);
  }
  const unsigned char* base = wsp + (size_t)qg * S * OBLK_BYTES;
  float acc = 0.f;
#pragma unroll
  for (int s = 0; s < S; ++s) {
    const float wgt = exp2f(mrow[s] - mg);
    const unsigned short ob =
        *(const unsigned short*)(base + (size_t)s * OBLK_BYTES + 2 * (dv * 32 + ql));
    acc += wgt * bf2f(ob);
  }
  out[(size_t)q * D + dv] = acc / L;
}

extern "C" void kernel_launch(void* const* d_in, const int* in_sizes, int n_in,
                              void* d_out, int out_size, void* d_ws, size_t ws_size,
                              hipStream_t stream)
{
  const float* qp = (const float*)d_in[0];
  const float* kp = (const float*)d_in[1];
  const float* vp = (const float*)d_in[2];
  const float* Kc = (const float*)d_in[3];
  const float* Vc = (const float*)d_in[4];
  float* out = (float*)d_out;
  unsigned char* ws = (unsigned char*)d_ws;

  // ws layout: [0, KV_BYTES) prepacked KV | O partials | m,l dense
  static const int cands[] = {128, 64, 32, 16, 8};
  int ksplit = 8;
  for (int i = 0; i < 5; ++i) {
    size_t need = KV_BYTES + (size_t)32 * cands[i] * OBLK_BYTES +
                  (size_t)2 * NQ * cands[i] * 4;
    if (need <= ws_size) { ksplit = cands[i]; break; }
  }

  mt_prepack<<<dim3(TILES_TOTAL), dim3(256), 0, stream>>>(Kc, Vc, kp, vp, ws);
  mt_attn_main<<<dim3(8 * ksplit), dim3(256), 0, stream>>>(qp, ws, ws, ksplit);

  const dim3 cgrid((NQ * D) / 256), cblk(256);
  switch (ksplit) {
    case 128: mt_attn_combine<128><<<cgrid, cblk, 0, stream>>>(ws, out); break;
    case 64:  mt_attn_combine<64><<<cgrid, cblk, 0, stream>>>(ws, out); break;
    case 32:  mt_attn_combine<32><<<cgrid, cblk, 0, stream>>>(ws, out); break;
    case 16:  mt_attn_combine<16><<<cgrid, cblk, 0, stream>>>(ws, out); break;
    default:  mt_attn_combine<8><<<cgrid, cblk, 0, stream>>>(ws, out); break;
  }
}

// Round 7
// 68.071 us; speedup vs baseline: 3.0714x; 1.0347x over previous
//
#include <hip/hip_runtime.h>

#define S_CACHE 32768
#define NQ 1024
#define D 128
#define KVB 32
#define TILES_TOTAL 1056
#define OBLK_BYTES 8192     // per (qg32, split): O^T packed u32 [chunk][32 q]
#define KV_TILE_BYTES 16384 // prepacked K frags (8 KB) + V frags (8 KB)
#define KV_BYTES ((size_t)TILES_TOTAL * KV_TILE_BYTES)  // 17,301,504

typedef float f32x4 __attribute__((ext_vector_type(4)));
typedef short s16x8 __attribute__((ext_vector_type(8)));
typedef int   i32x4 __attribute__((ext_vector_type(4)));

static __device__ __forceinline__ int cvtpk(float lo, float hi) {
  int r;
  asm("v_cvt_pk_bf16_f32 %0, %1, %2" : "=v"(r) : "v"(lo), "v"(hi));
  return r;
}
static __device__ __forceinline__ s16x8 frag4(int a, int b, int c, int d) {
  i32x4 t = {a, b, c, d};
  return __builtin_bit_cast(s16x8, t);
}
static __device__ __forceinline__ float bf2f(unsigned int b) {
  return __uint_as_float(b << 16);
}
// async global->LDS, 16B per lane; lds dest is wave-uniform base + lane*16
static __device__ __forceinline__ void llds16(const unsigned char* g, unsigned char* l) {
  __builtin_amdgcn_global_load_lds(
      (const __attribute__((address_space(1))) unsigned int*)g,
      (__attribute__((address_space(3))) unsigned int*)l, 16, 0, 0);
}

// ---------------------------------------------------------------------------
// Prepack: K/V f32 -> bf16 in the exact MFMA-fragment LDS image order.
// Tile t (16 KB): [0,8K): K chunk (h*4+c), lane (g,qq):
//   K[t*32 + 8*(qq>>2)+(qq&3)+4h][32c+8g..+7]; [8K,16K): V chunk dt:
//   V[t*32+8g+i][16dt+qq], i=0..7.
// ---------------------------------------------------------------------------
__global__ __launch_bounds__(256) void mt_prepack(
    const float* __restrict__ Kc, const float* __restrict__ Vc,
    const float* __restrict__ knew, const float* __restrict__ vnew,
    unsigned char* __restrict__ kv)
{
  const int t = blockIdx.x;
  const int t32 = t * KVB;
  const float* Kb = (t32 < S_CACHE) ? Kc + (size_t)t32 * D
                                    : knew + (size_t)(t32 - S_CACHE) * D;
  const float* Vb = (t32 < S_CACHE) ? Vc + (size_t)t32 * D
                                    : vnew + (size_t)(t32 - S_CACHE) * D;
  unsigned char* outb = kv + (size_t)t * KV_TILE_BYTES;
#pragma unroll
  for (int rep = 0; rep < 4; ++rep) {
    const int id = rep * 256 + threadIdx.x;
    const int chunk = id >> 6;   // uniform per wave
    const int l  = id & 63;
    const int g  = l >> 4, qq = l & 15;
    i32x4 outv;
    if (chunk < 8) {
      const int h = chunk >> 2, c = chunk & 3;
      const int krow = 8 * (qq >> 2) + (qq & 3) + 4 * h;
      const float* src = Kb + (size_t)krow * D + 32 * c + 8 * g;
      f32x4 x0 = *(const f32x4*)src;
      f32x4 x1 = *(const f32x4*)(src + 4);
      outv = i32x4{cvtpk(x0[0], x0[1]), cvtpk(x0[2], x0[3]),
                   cvtpk(x1[0], x1[1]), cvtpk(x1[2], x1[3])};
    } else {
      const int dt = chunk - 8;
      float v[8];
#pragma unroll
      for (int i = 0; i < 8; ++i)
        v[i] = Vb[(size_t)(8 * g + i) * D + 16 * dt + qq];
      outv = i32x4{cvtpk(v[0], v[1]), cvtpk(v[2], v[3]),
                   cvtpk(v[4], v[5]), cvtpk(v[6], v[7])};
    }
    *(i32x4*)(outb + (size_t)chunk * 1024 + l * 16) = outv;
  }
}

// ---------------------------------------------------------------------------
// Main: grid 8*KSPLIT blocks (KSPLIT=32 -> 256 = 1/CU), 256 thr = 4 waves.
// XCD co-location: split s = (n&7)+8*(n>>6) -> its 8 q-blocks on one XCD/L2.
// Counted-vmcnt deep pipeline (T3/T4): 4 LDS buffers, 3 tiles in flight;
// per tile: s_waitcnt vmcnt(8) + raw s_barrier (NEVER vmcnt(0) in the loop),
// epilogue peel drains 8/4/0. Swapped-operand flash attn, lane-local softmax.
// ---------------------------------------------------------------------------
template <int KSPLIT>
__global__ __launch_bounds__(256) void mt_attn_main(
    const float* __restrict__ qp, const unsigned char* __restrict__ kv,
    unsigned char* __restrict__ ws)
{
  constexpr int TILES = TILES_TOTAL / KSPLIT;  // 33 for KSPLIT=32
  static_assert(TILES * KSPLIT == TILES_TOTAL, "KSPLIT must divide 1056");
  static_assert(TILES >= 4, "pipeline needs >=4 tiles");
  __shared__ __align__(16) unsigned char lds[4][KV_TILE_BYTES];  // 64 KB

  const int tid  = threadIdx.x;
  const int lane = tid & 63;
  const int w    = tid >> 6;
  const int g    = lane >> 4;
  const int qq   = lane & 15;

  const int n    = blockIdx.x;
  const int s    = (n & 7) + 8 * (n >> 6);   // split, pinned to XCD s%8
  const int qg   = (n >> 3) & 7;
  const int qg32 = qg * 4 + w;               // 32-q group per wave
  const int t_st = s * TILES;

  // ---- Q fragments (B-operand): lane holds Q[q][32c+8g+i], scaled ----
  const float QSCALE = 0.0883883476483184f * 1.4426950408889634f;  // 1/sqrt(128)*log2(e)
  s16x8 qf[2][4];
#pragma unroll
  for (int u = 0; u < 2; ++u) {
    const float* qrow = qp + (size_t)(qg32 * 32 + u * 16 + qq) * D + 8 * g;
#pragma unroll
    for (int c = 0; c < 4; ++c) {
      f32x4 x0 = *(const f32x4*)(qrow + 32 * c);
      f32x4 x1 = *(const f32x4*)(qrow + 32 * c + 4);
      qf[u][c] = frag4(cvtpk(x0[0] * QSCALE, x0[1] * QSCALE),
                       cvtpk(x0[2] * QSCALE, x0[3] * QSCALE),
                       cvtpk(x1[0] * QSCALE, x1[1] * QSCALE),
                       cvtpk(x1[2] * QSCALE, x1[3] * QSCALE));
    }
  }

  f32x4 oacc[2][8];
#pragma unroll
  for (int u = 0; u < 2; ++u)
#pragma unroll
    for (int dt = 0; dt < 8; ++dt) {
      f32x4 z = {0.f, 0.f, 0.f, 0.f};
      oacc[u][dt] = z;
    }
  float mrun[2] = {-1e30f, -1e30f};
  float lrun[2] = {0.f, 0.f};

  auto stage_issue = [&](int tile, int b) {
    const unsigned char* src =
        kv + (size_t)(t_st + tile) * KV_TILE_BYTES + w * 1024 + lane * 16;
    unsigned char* dst = &lds[b][w * 1024];
#pragma unroll
    for (int r = 0; r < 4; ++r)
      llds16(src + r * 4096, dst + r * 4096);
  };

  auto compute = [&](int tile) {
    const int buf = tile & 3;
    const int t32 = (t_st + tile) * KVB;
    // ---- QK^T (swapped): lane(g,qq) -> scores for q=qq, keys 8g+n ----
    f32x4 sc[2][2];
#pragma unroll
    for (int u = 0; u < 2; ++u)
#pragma unroll
      for (int h = 0; h < 2; ++h) {
        f32x4 z = {0.f, 0.f, 0.f, 0.f};
        sc[u][h] = z;
      }
#pragma unroll
    for (int h = 0; h < 2; ++h)
#pragma unroll
      for (int c = 0; c < 4; ++c) {
        s16x8 kf = *(const s16x8*)(&lds[buf][(size_t)((h * 4 + c) * 64 + lane) * 16]);
        sc[0][h] = __builtin_amdgcn_mfma_f32_16x16x32_bf16(kf, qf[0][c], sc[0][h], 0, 0, 0);
        sc[1][h] = __builtin_amdgcn_mfma_f32_16x16x32_bf16(kf, qf[1][c], sc[1][h], 0, 0, 0);
      }
    // ---- softmax (base-2, lane-local rows) ----
    s16x8 pf[2];
#pragma unroll
    for (int u = 0; u < 2; ++u) {
      float sv[8];
#pragma unroll
      for (int h = 0; h < 2; ++h)
#pragma unroll
        for (int r = 0; r < 4; ++r)
          sv[4 * h + r] = sc[u][h][r];
      if (t32 >= S_CACHE) {  // causal mask (uniform branch per tile)
        const int qglob = qg32 * 32 + u * 16 + qq;
#pragma unroll
        for (int nn = 0; nn < 8; ++nn) {
          const int key = t32 + 8 * g + nn;
          if (key - S_CACHE > qglob) sv[nn] = -1e30f;
        }
      }
      float vmax = fmaxf(fmaxf(fmaxf(sv[0], sv[1]), fmaxf(sv[2], sv[3])),
                         fmaxf(fmaxf(sv[4], sv[5]), fmaxf(sv[6], sv[7])));
      vmax = fmaxf(vmax, __shfl_xor(vmax, 16, 64));
      vmax = fmaxf(vmax, __shfl_xor(vmax, 32, 64));
      if (!__all(vmax <= mrun[u] + 8.f)) {  // defer-max
        const float mnew = fmaxf(mrun[u], vmax);
        const float corr = exp2f(mrun[u] - mnew);
        lrun[u] *= corr;
#pragma unroll
        for (int dt = 0; dt < 8; ++dt) oacc[u][dt] *= corr;
        mrun[u] = mnew;
      }
      float p[8], rs = 0.f;
#pragma unroll
      for (int nn = 0; nn < 8; ++nn) {
        p[nn] = exp2f(sv[nn] - mrun[u]);
        rs += p[nn];
      }
      rs += __shfl_xor(rs, 16, 64);
      rs += __shfl_xor(rs, 32, 64);
      lrun[u] += rs;
      pf[u] = frag4(cvtpk(p[0], p[1]), cvtpk(p[2], p[3]),
                    cvtpk(p[4], p[5]), cvtpk(p[6], p[7]));
    }
    // ---- PV (swapped): O^T += V^T @ P^T ----
#pragma unroll
    for (int dt = 0; dt < 8; ++dt) {
      s16x8 vf = *(const s16x8*)(&lds[buf][(size_t)(8192 + (dt * 64 + lane) * 16)]);
      oacc[0][dt] = __builtin_amdgcn_mfma_f32_16x16x32_bf16(vf, pf[0], oacc[0][dt], 0, 0, 0);
      oacc[1][dt] = __builtin_amdgcn_mfma_f32_16x16x32_bf16(vf, pf[1], oacc[1][dt], 0, 0, 0);
    }
  };

  // ---- deep pipeline: 3 tiles in flight, counted vmcnt ----
  stage_issue(0, 0);
  stage_issue(1, 1);
  stage_issue(2, 2);
  for (int tile = 0; tile < TILES - 3; ++tile) {
    asm volatile("s_waitcnt vmcnt(8)" ::: "memory");  // own tile-t loads done
    __builtin_amdgcn_s_barrier();                     // all waves' too
    stage_issue(tile + 3, (tile + 3) & 3);            // overwrites buf[tile-1]: safe
    compute(tile);
  }
  asm volatile("s_waitcnt vmcnt(8)" ::: "memory");
  __builtin_amdgcn_s_barrier();
  compute(TILES - 3);
  asm volatile("s_waitcnt vmcnt(4)" ::: "memory");
  __builtin_amdgcn_s_barrier();
  compute(TILES - 2);
  asm volatile("s_waitcnt vmcnt(0)" ::: "memory");
  __builtin_amdgcn_s_barrier();
  compute(TILES - 1);

  // ---- partials: packed u32 O^T (full-line stores) + dense m,l ----
  unsigned char* wsp = ws + KV_BYTES;
  unsigned int* pO = (unsigned int*)(wsp + (size_t)(qg32 * KSPLIT + s) * OBLK_BYTES);
  float* m_ws = (float*)(wsp + (size_t)32 * KSPLIT * OBLK_BYTES);
  float* l_ws = m_ws + (size_t)NQ * KSPLIT;
#pragma unroll
  for (int u = 0; u < 2; ++u) {
#pragma unroll
    for (int dt = 0; dt < 8; ++dt)
#pragma unroll
      for (int r2 = 0; r2 < 2; ++r2)
        pO[(8 * dt + 2 * g + r2) * 32 + u * 16 + qq] =
            (unsigned int)cvtpk(oacc[u][dt][2 * r2], oacc[u][dt][2 * r2 + 1]);
    if (g == 0) {
      const int q = qg32 * 32 + u * 16 + qq;
      m_ws[(size_t)q * KSPLIT + s] = mrun[u];
      l_ws[(size_t)q * KSPLIT + s] = lrun[u];
    }
  }
}

// ---------------------------------------------------------------------------
// Combine, templated on SPLITS for full unroll. One thread per (q, dv).
// ---------------------------------------------------------------------------
template <int S>
__global__ __launch_bounds__(256) void mt_attn_combine(
    const unsigned char* __restrict__ ws, float* __restrict__ out)
{
  const int t  = blockIdx.x * 256 + threadIdx.x;  // 131072 total
  const int ql = t & 31;
  const int dv = (t >> 5) & 127;
  const int qg = t >> 12;
  const int q  = qg * 32 + ql;

  const unsigned char* wsp = ws + KV_BYTES;
  const float* m_ws = (const float*)(wsp + (size_t)32 * S * OBLK_BYTES);
  const float* l_ws = m_ws + (size_t)NQ * S;
  const float* mrow = m_ws + (size_t)q * S;
  const float* lrow = l_ws + (size_t)q * S;

  float mg = -1e30f;
#pragma unroll
  for (int s4 = 0; s4 < S / 4; ++s4) {
    f32x4 m4 = *(const f32x4*)(mrow + 4 * s4);
    mg = fmaxf(mg, fmaxf(fmaxf(m4[0], m4[1]), fmaxf(m4[2], m4[3])));
  }
  float L = 0.f;
#pragma unroll
  for (int s4 = 0; s4 < S / 4; ++s4) {
    f32x4 m4 = *(const f32x4*)(mrow + 4 * s4);
    f32x4 l4 = *(const f32x4*)(lrow + 4 * s4);
    L += l4[0] * exp2f(m4[0] - mg) + l4[1] * exp2f(m4[1] - mg) +
         l4[2] * exp2f(m4[2] - mg) + l4[3] * exp2f(m4[3] - mg);
  }
  // packed-O read: dv -> (dt, g, r); word (8dt+2g+(r>>1))*32 + ql, half r&1
  const int dt = dv >> 4, g2 = (dv >> 2) & 3, r = dv & 3;
  const int word = (8 * dt + 2 * g2 + (r >> 1)) * 32 + ql;
  const int sh = (r & 1) * 16;
  const unsigned int* base =
      (const unsigned int*)(wsp + (size_t)qg * S * OBLK_BYTES) + word;
  float acc = 0.f;
#pragma unroll
  for (int s = 0; s < S; ++s) {
    const float wgt = exp2f(mrow[s] - mg);
    acc += wgt * bf2f((base[(size_t)s * (OBLK_BYTES / 4)] >> sh) & 0xffffu);
  }
  out[(size_t)q * D + dv] = acc / L;
}

extern "C" void kernel_launch(void* const* d_in, const int* in_sizes, int n_in,
                              void* d_out, int out_size, void* d_ws, size_t ws_size,
                              hipStream_t stream)
{
  const float* qp = (const float*)d_in[0];
  const float* kp = (const float*)d_in[1];
  const float* vp = (const float*)d_in[2];
  const float* Kc = (const float*)d_in[3];
  const float* Vc = (const float*)d_in[4];
  float* out = (float*)d_out;
  unsigned char* ws = (unsigned char*)d_ws;

  // ws: [0, KV_BYTES) prepacked KV | O partials | m,l dense
  static const int cands[] = {32, 16, 8};
  int ksplit = 8;
  for (int i = 0; i < 3; ++i) {
    size_t need = KV_BYTES + (size_t)32 * cands[i] * OBLK_BYTES +
                  (size_t)2 * NQ * cands[i] * 4;
    if (need <= ws_size) { ksplit = cands[i]; break; }
  }

  mt_prepack<<<dim3(TILES_TOTAL), dim3(256), 0, stream>>>(Kc, Vc, kp, vp, ws);

  const dim3 cgrid((NQ * D) / 256), cblk(256);
  switch (ksplit) {
    case 32:
      mt_attn_main<32><<<dim3(256), dim3(256), 0, stream>>>(qp, ws, ws);
      mt_attn_combine<32><<<cgrid, cblk, 0, stream>>>(ws, out);
      break;
    case 16:
      mt_attn_main<16><<<dim3(128), dim3(256), 0, stream>>>(qp, ws, ws);
      mt_attn_combine<16><<<cgrid, cblk, 0, stream>>>(ws, out);
      break;
    default:
      mt_attn_main<8><<<dim3(64), dim3(256), 0, stream>>>(qp, ws, ws);
      mt_attn_combine<8><<<cgrid, cblk, 0, stream>>>(ws, out);
      break;
  }
}